// Round 5
// baseline (26.093 us; speedup 1.0000x reference)
//
#include <hip/hip_runtime.h>
#include <hip/hip_bf16.h>

typedef short bf16x8 __attribute__((ext_vector_type(8)));
typedef float f32x4 __attribute__((ext_vector_type(4)));

#define LG2G (-0.045803689613125f)   /* log2(0.96875) */
#define BATCH 4
#define SEQ 4096
#define DIM 64
#define BAND 5                       /* m-tiles of 64 kept before the diagonal */

__device__ __forceinline__ ushort f2bf(float x){
  union { float f; unsigned u; } v; v.f = x;
  unsigned r = v.u + 0x7fffu + ((v.u >> 16) & 1u);
  return (ushort)(r >> 16);
}

// xpos phase factors for pair i (0..31) at position s, via HW transcendentals
__device__ __forceinline__ void xpos_sc(int i, float fs, float& sn, float& cs, float& scale){
  float base = ((float)(2 * i) + 25.6f) * (1.0f / 89.6f);
  scale = exp2f(log2f(base) * (fs * (1.0f / 512.0f)));
  float invf = exp2f((float)i * -0.4152410118609203f);   // 10000^(-i/32)
  float rev = fs * invf * 0.15915494309189535f;          // radians -> revolutions
  rev = rev - floorf(rev);
  asm("v_sin_f32 %0, %1" : "=v"(sn) : "v"(rev));
  asm("v_cos_f32 %0, %1" : "=v"(cs) : "v"(rev));
}

// ---- kernel 1: prep k (xpos * gamma^-(s&63)) and V^T, bf16 ----
// grid 256 x 512: each block 2 float4-chunk strides of k + one 64x64 V tile.
__global__ __launch_bounds__(512) void prep(const float* __restrict__ K,
                                            const float* __restrict__ V,
                                            ushort* __restrict__ kb,
                                            ushort* __restrict__ vt){
  __shared__ ushort vtile[64][65];
  int bx = blockIdx.x;
  int t = threadIdx.x;

  // k xpos: chunks cid = bx*512 + t + it*131072  (B*S*16 = 262144 total)
  #pragma unroll
  for (int it = 0; it < 2; ++it){
    int cid = (bx + it * 256) * 512 + t;
    int row = cid >> 4;                  // b*4096 + s
    int pp = cid & 15;
    int s = row & (SEQ - 1);
    float fs = (float)s;
    float kg = exp2f((float)(-(s & 63)) * LG2G);  // gamma^-(s&63)
    float4 kv = ((const float4*)K)[cid];
    unsigned ko[2];
    #pragma unroll
    for (int u = 0; u < 2; ++u){
      float sn, cs, sc;
      xpos_sc(pp * 2 + u, fs, sn, cs, sc);
      float isc = kg / sc;
      float ssk = sn * isc, csk = cs * isc;
      float y0 = u ? kv.z : kv.x, y1 = u ? kv.w : kv.y;
      asm("v_cvt_pk_bf16_f32 %0, %1, %2" : "=v"(ko[u])
          : "v"(y0 * csk - y1 * ssk), "v"(y1 * csk + y0 * ssk));
    }
    ((uint2*)kb)[cid] = make_uint2(ko[0], ko[1]);
  }

  // V transpose: block bx -> tile (b = bx>>6, s0 = (bx&63)*64)
  {
    int b = bx >> 6, st = bx & 63;
    int s0 = st * 64;
    int v = t & 63, sl = t >> 6;         // sl = 0..7
    #pragma unroll
    for (int it = 0; it < 8; ++it){
      int s = sl + it * 8;
      vtile[s][v] = f2bf(V[((size_t)(b * SEQ + s0 + s)) * 64 + v]);
    }
    __syncthreads();
    int s2 = t & 63, vq = t >> 6;
    #pragma unroll
    for (int it = 0; it < 8; ++it){
      int v2 = vq + it * 8;
      vt[((size_t)(b * 64 + v2)) * SEQ + s0 + s2] = vtile[s2][v2];
    }
  }
}

// ---- kernel 2: banded flash retention (self-prepped q in LDS) ----
// grid 512 = b(4) x btile(64) x half(2); block 512 = 8 waves; 2 blocks/CU.
// Step 0: each thread xpos-preps ONE float4 chunk of its block's own 32 q rows
//         (chunk tid = bx*512 + t -> row bx*32 + (t>>4)) -> qlds. __syncthreads.
// Then: swapped-QK^T banded retention with operand-folded decay (round-3 form).
__global__ __launch_bounds__(512, 4) void retention(const float* __restrict__ Q,
                                                    const ushort* __restrict__ kb,
                                                    const ushort* __restrict__ vt,
                                                    float* __restrict__ out){
  __shared__ ushort qlds[32][64];        // this block's q strip (bf16)
  __shared__ ushort Pbuf[8][16][72];     // per-wave P strip [qrow][m], padded
  __shared__ float  Obuf[2][3][16][65];  // partial-O combine buffers

  int bx = blockIdx.x;
  int t = threadIdx.x;

  // ---- step 0: q prep (rows bx*32 .. bx*32+31) ----
  {
    int tid = bx * 512 + t;              // float4 chunk id, 1:1 with threads
    int pp = tid & 15;
    int s = (tid >> 4) & (SEQ - 1);
    float fs = (float)s;
    float qg = exp2f((float)(s & 63) * LG2G);     // gamma^(s&63)
    float4 qv = ((const float4*)Q)[tid];
    unsigned qo[2];
    #pragma unroll
    for (int u = 0; u < 2; ++u){
      float sn, cs, sc;
      xpos_sc(pp * 2 + u, fs, sn, cs, sc);
      float ssq = sn * sc * qg, csq = cs * sc * qg;
      float x0 = u ? qv.z : qv.x, x1 = u ? qv.w : qv.y;
      asm("v_cvt_pk_bf16_f32 %0, %1, %2" : "=v"(qo[u])
          : "v"(x0 * csq - x1 * ssq), "v"(x1 * csq + x0 * ssq));
    }
    *(uint2*)&qlds[t >> 4][pp * 4] = make_uint2(qo[0], qo[1]);
  }
  __syncthreads();

  // ---- retention ----
  int b = bx >> 7;
  int rest = bx & 127;
  int btile = rest >> 1, half = rest & 1;
  int wave = t >> 6, lane = t & 63;
  int j = wave & 1, h = wave >> 1;
  int g = lane >> 4, c = lane & 15;
  int r0 = btile * 64 + half * 32 + j * 16;     // strip row within batch
  size_t rowbase = (size_t)b * SEQ + r0;
  int t0 = btile >= BAND ? btile - BAND : 0;    // decay cutoff 320
  int t1 = btile;

  // q fragments from LDS (strip row = j*16 + c, k = kk*32 + g*8 + [0..7])
  bf16x8 bq0 = *(const bf16x8*)(&qlds[j * 16 + c][g * 8]);
  bf16x8 bq1 = *(const bf16x8*)(&qlds[j * 16 + c][g * 8 + 32]);

  f32x4 acc_o[4];
  #pragma unroll
  for (int vb = 0; vb < 4; ++vb) acc_o[vb] = (f32x4)0.0f;

  float tilefac = exp2f((float)(64 * (btile - t0 - h)) * LG2G);
  const float tstep = 3386.8804f;               // gamma^-256 (4-tile stride)

  for (int tt = t0 + h; tt <= t1; tt += 4){
    int m0 = tt * 64;

    // S''^T = mfma(k', q'): lane (g,c) gets S''[q row c][m0 + nb*16 + g*4 + r]
    const ushort* kbase = kb + ((size_t)b * SEQ + m0 + c) * 64 + g * 8;
    f32x4 st[4];
    #pragma unroll
    for (int nb = 0; nb < 4; ++nb){
      bf16x8 ak0 = *(const bf16x8*)(kbase + (size_t)nb * 1024);
      bf16x8 ak1 = *(const bf16x8*)(kbase + (size_t)nb * 1024 + 32);
      st[nb] = (f32x4)0.0f;
      st[nb] = __builtin_amdgcn_mfma_f32_16x16x32_bf16(ak0, bq0, st[nb], 0, 0, 0);
      st[nb] = __builtin_amdgcn_mfma_f32_16x16x32_bf16(ak1, bq1, st[nb], 0, 0, 0);
    }

    // P = S'' * tilefac (wave-uniform); causal mask on diagonal tile only
    #pragma unroll
    for (int nb = 0; nb < 4; ++nb)
      #pragma unroll
      for (int r = 0; r < 4; ++r)
        st[nb][r] *= tilefac;
    if (tt == t1){
      int drow = r0 + c - m0;
      #pragma unroll
      for (int nb = 0; nb < 4; ++nb)
        #pragma unroll
        for (int r = 0; r < 4; ++r)
          if (drow < nb * 16 + g * 4 + r) st[nb][r] = 0.0f;
    }

    // pack pairs (RNE) + vector LDS write: 4 x ds_write_b64 per tile
    #pragma unroll
    for (int nb = 0; nb < 4; ++nb){
      unsigned w0, w1;
      asm("v_cvt_pk_bf16_f32 %0, %1, %2" : "=v"(w0) : "v"(st[nb][0]), "v"(st[nb][1]));
      asm("v_cvt_pk_bf16_f32 %0, %1, %2" : "=v"(w1) : "v"(st[nb][2]), "v"(st[nb][3]));
      *(uint2*)&Pbuf[wave][c][nb * 16 + g * 4] = make_uint2(w0, w1);
    }

    // P A-fragments (row = c, k = kk*32 + g*8 + [0..7])
    bf16x8 ap0 = *(const bf16x8*)(&Pbuf[wave][c][g * 8]);
    bf16x8 ap1 = *(const bf16x8*)(&Pbuf[wave][c][32 + g * 8]);

    // O += P * V   (B from V^T: col = v = vb*16+c, k = m contiguous)
    const ushort* vbase = vt + ((size_t)b * 64 + c) * SEQ + m0 + g * 8;
    #pragma unroll
    for (int vb = 0; vb < 4; ++vb){
      bf16x8 bv0 = *(const bf16x8*)(vbase + (size_t)vb * 16 * SEQ);
      bf16x8 bv1 = *(const bf16x8*)(vbase + (size_t)vb * 16 * SEQ + 32);
      acc_o[vb] = __builtin_amdgcn_mfma_f32_16x16x32_bf16(ap0, bv0, acc_o[vb], 0, 0, 0);
      acc_o[vb] = __builtin_amdgcn_mfma_f32_16x16x32_bf16(ap1, bv1, acc_o[vb], 0, 0, 0);
    }

    tilefac *= tstep;
  }

  // combine the four m-classes (waves h=0..3 per strip j), then store
  if (h > 0){
    #pragma unroll
    for (int vb = 0; vb < 4; ++vb)
      #pragma unroll
      for (int r = 0; r < 4; ++r)
        Obuf[j][h - 1][g * 4 + r][vb * 16 + c] = acc_o[vb][r];
  }
  __syncthreads();
  if (h == 0){
    #pragma unroll
    for (int vb = 0; vb < 4; ++vb)
      #pragma unroll
      for (int r = 0; r < 4; ++r){
        float val = acc_o[vb][r]
                  + Obuf[j][0][g * 4 + r][vb * 16 + c]
                  + Obuf[j][1][g * 4 + r][vb * 16 + c]
                  + Obuf[j][2][g * 4 + r][vb * 16 + c];
        out[(rowbase + g * 4 + r) * 64 + vb * 16 + c] = val;
      }
  }
}

extern "C" void kernel_launch(void* const* d_in, const int* in_sizes, int n_in,
                              void* d_out, int out_size, void* d_ws, size_t ws_size,
                              hipStream_t stream){
  (void)in_sizes; (void)n_in; (void)out_size; (void)ws_size;
  const float* Q = (const float*)d_in[0];
  const float* K = (const float*)d_in[1];
  const float* V = (const float*)d_in[2];
  float* out = (float*)d_out;

  ushort* kb = (ushort*)d_ws;                       // 2 MB
  ushort* vt = kb + (size_t)BATCH * SEQ * DIM;      // 2 MB

  hipLaunchKernelGGL(prep, dim3(256), dim3(512), 0, stream, K, V, kb, vt);
  hipLaunchKernelGGL(retention, dim3(BATCH * 128), dim3(512), 0, stream, Q, kb, vt, out);
}

// Round 6
// 17.126 us; speedup vs baseline: 1.5235x; 1.5235x over previous
//
#include <hip/hip_runtime.h>

typedef short bf16x8 __attribute__((ext_vector_type(8)));
typedef float f32x4 __attribute__((ext_vector_type(4)));

#define LG2G (-0.045803689613125f)   /* log2(0.96875) */
#define SEQ 4096
#define BAND 5                       /* m-tiles of 64 kept before the diagonal */
#define NTMAX (BAND + 1)

__device__ __forceinline__ unsigned pkbf(float a, float b){
  unsigned r; asm("v_cvt_pk_bf16_f32 %0, %1, %2" : "=v"(r) : "v"(a), "v"(b)); return r;
}
__device__ __forceinline__ unsigned rot_pack(float x0, float x1, float s, float c){
  return pkbf(x0*c - x1*s, x1*c + x0*s);
}
__device__ __forceinline__ float hw_sin(float rev){ float r; asm("v_sin_f32 %0, %1":"=v"(r):"v"(rev)); return r; }
__device__ __forceinline__ float hw_cos(float rev){ float r; asm("v_cos_f32 %0, %1":"=v"(r):"v"(rev)); return r; }

// Single fused kernel. grid 256 = b(4) x btile(64); block 512 = 8 waves =
// (strip j 0..3) x (tile-parity e 0..1). Each block self-stages everything:
//   q  -> registers (lane (g,c) of strip j IS q row j*16+c)
//   k' -> klds  [tile][row m][d]   bf16, xpos * gamma^-(m&63), XOR-swizzled
//   V  -> vlds  [tile][v][m]       bf16 transposed, XOR-swizzled
// Phase 2 is barrier-free: wave (j,e) does tiles ttl = e, e+2, ... with a
// PRIVATE P-strip in LDS (same-wave write->read, lgkmcnt-ordered). One final
// barrier combines the two parity partials per strip.
template<int NTC>
__device__ __forceinline__ void body(
    int nt, int t0, size_t boff, int btile, int t,
    const float* __restrict__ Q, const float* __restrict__ K,
    const float* __restrict__ V, float* __restrict__ out,
    char* kl, char* vl, ushort* Pb, float* Ob)
{
  int wave = t >> 6, lane = t & 63;
  int j = wave >> 1, e = wave & 1;
  int g = lane >> 4, c = lane & 15;
  const int NITER = NTC ? NTC : nt;

  // ---- phase 1A: q fragments straight to registers ----
  bf16x8 bq0, bq1;
  {
    int qrow = btile*64 + j*16 + c;
    const float* qp = Q + (boff + qrow)*64;
    float4 a0 = *(const float4*)(qp + g*8);
    float4 a1 = *(const float4*)(qp + g*8 + 4);
    float4 a2 = *(const float4*)(qp + 32 + g*8);
    float4 a3 = *(const float4*)(qp + 32 + g*8 + 4);
    float fs = (float)qrow;
    float qg = exp2f((float)(j*16 + c) * LG2G);      // gamma^(row&63)
    float p0[8] = {a0.x,a0.y,a0.z,a0.w,a1.x,a1.y,a1.z,a1.w};
    float p1[8] = {a2.x,a2.y,a2.z,a2.w,a3.x,a3.y,a3.z,a3.w};
    union { unsigned u[4]; bf16x8 v; } U0, U1;
    #pragma unroll
    for (int u = 0; u < 4; ++u){
      {
        int i = g*4 + u;
        float lb = log2f(((float)(2*i) + 25.6f) * (1.0f/89.6f));
        float sc = exp2f(lb * fs * (1.0f/512.0f)) * qg;
        float rev = fs * exp2f((float)i * -0.4152410118609203f) * 0.15915494309189535f;
        rev -= floorf(rev);
        U0.u[u] = rot_pack(p0[2*u], p0[2*u+1], hw_sin(rev)*sc, hw_cos(rev)*sc);
      }
      {
        int i = 16 + g*4 + u;
        float lb = log2f(((float)(2*i) + 25.6f) * (1.0f/89.6f));
        float sc = exp2f(lb * fs * (1.0f/512.0f)) * qg;
        float rev = fs * exp2f((float)i * -0.4152410118609203f) * 0.15915494309189535f;
        rev -= floorf(rev);
        U1.u[u] = rot_pack(p1[2*u], p1[2*u+1], hw_sin(rev)*sc, hw_cos(rev)*sc);
      }
    }
    bq0 = U0.v; bq1 = U1.v;
  }

  // ---- phase 1B: k tiles -> klds (xpos * gamma^-(row), swizzled) ----
  {
    int krow = t >> 3, dk = t & 7;                   // row 0..63, 8-float d-chunk
    float kfold = exp2f((float)(-krow) * LG2G);      // gamma^-(m&63)
    float lbn[4], ivf[4];
    #pragma unroll
    for (int u = 0; u < 4; ++u){
      int i = dk*4 + u;
      lbn[u] = log2f(((float)(2*i) + 25.6f) * (1.0f/89.6f)) * (-1.0f/512.0f);
      ivf[u] = exp2f((float)i * -0.4152410118609203f) * 0.15915494309189535f;
    }
    int woff = krow*128 + ((dk ^ (krow & 7)) << 4);  // XOR swizzle, 16B units
    #pragma unroll
    for (int ttl = 0; ttl < NITER; ++ttl){
      int m = (t0 + ttl)*64 + krow;
      const float* kp = K + (boff + m)*64 + dk*8;
      float4 b0 = *(const float4*)kp;
      float4 b1 = *(const float4*)(kp + 4);
      float fs = (float)m;
      float px[8] = {b0.x,b0.y,b0.z,b0.w,b1.x,b1.y,b1.z,b1.w};
      unsigned w[4];
      #pragma unroll
      for (int u = 0; u < 4; ++u){
        float sc = exp2f(lbn[u]*fs) * kfold;         // (1/scale) * gamma^-(row)
        float rev = fs * ivf[u]; rev -= floorf(rev);
        w[u] = rot_pack(px[2*u], px[2*u+1], hw_sin(rev)*sc, hw_cos(rev)*sc);
      }
      *(uint4*)(kl + ttl*8192 + woff) = make_uint4(w[0],w[1],w[2],w[3]);
    }
  }

  // ---- phase 1C: V tiles -> vlds transposed [v][m] (swizzled) ----
  {
    #pragma unroll
    for (int pass = 0; pass < 3; ++pass){
      int u = t + pass*512;
      int tile = u >> 8;
      if (tile < NITER){
        int rem = u & 255, m4 = rem >> 4, v4 = rem & 15;
        const float* vp = V + (boff + (size_t)(t0 + tile)*64 + m4*4)*64 + v4*4;
        float4 r0 = *(const float4*)vp;
        float4 r1 = *(const float4*)(vp + 64);
        float4 r2 = *(const float4*)(vp + 128);
        float4 r3 = *(const float4*)(vp + 192);
        float f0[4]={r0.x,r0.y,r0.z,r0.w}, f1[4]={r1.x,r1.y,r1.z,r1.w};
        float f2[4]={r2.x,r2.y,r2.z,r2.w}, f3[4]={r3.x,r3.y,r3.z,r3.w};
        #pragma unroll
        for (int jv = 0; jv < 4; ++jv){
          int v = v4*4 + jv;
          int off = tile*8192 + v*128 + (((m4 >> 1) ^ (v & 7)) << 4) + ((m4 & 1) << 3);
          *(uint2*)(vl + off) = make_uint2(pkbf(f0[jv], f1[jv]), pkbf(f2[jv], f3[jv]));
        }
      }
    }
  }
  __syncthreads();

  // ---- phase 2: barrier-free banded retention ----
  int sw = (c & 7) << 4;
  ushort* pw = Pb + wave * (16*72);                  // private P strip [16][72]
  float tilefac = exp2f((float)(64*(nt - 1 - e)) * LG2G);
  const float tstep2 = exp2f(-128.0f * LG2G);        // gamma^-128 (2-tile stride)
  f32x4 acc[4];
  #pragma unroll
  for (int vb = 0; vb < 4; ++vb) acc[vb] = (f32x4)0.0f;

  #pragma unroll
  for (int it = 0; it < (NTC ? (NTC+1)/2 : 3); ++it){
    int ttl = e + it*2;
    if (NTC ? true : (ttl < nt)){
      int base = ttl*8192;
      // S''^T = mfma(k', q'): lane (g,c) -> S''[qrow c][m = nb*16 + g*4 + r]
      f32x4 st[4];
      #pragma unroll
      for (int nb = 0; nb < 4; ++nb){
        int ro = (nb*16 + c)*128;
        bf16x8 ak0 = *(const bf16x8*)(kl + base + ro + ((g << 4) ^ sw));
        bf16x8 ak1 = *(const bf16x8*)(kl + base + ro + (((4+g) << 4) ^ sw));
        f32x4 z = (f32x4)0.0f;
        z = __builtin_amdgcn_mfma_f32_16x16x32_bf16(ak0, bq0, z, 0, 0, 0);
        z = __builtin_amdgcn_mfma_f32_16x16x32_bf16(ak1, bq1, z, 0, 0, 0);
        st[nb] = z;
      }
      #pragma unroll
      for (int nb = 0; nb < 4; ++nb)
        #pragma unroll
        for (int r = 0; r < 4; ++r) st[nb][r] *= tilefac;
      if (NTC ? (ttl == NTC-1) : (ttl == nt-1)){     // causal mask, diagonal only
        int qrl = j*16 + c;
        #pragma unroll
        for (int nb = 0; nb < 4; ++nb)
          #pragma unroll
          for (int r = 0; r < 4; ++r)
            if (qrl < nb*16 + g*4 + r) st[nb][r] = 0.0f;
      }
      // P -> private LDS strip (same-wave round trip, no barrier)
      #pragma unroll
      for (int nb = 0; nb < 4; ++nb)
        *(uint2*)&pw[c*72 + nb*16 + g*4] =
            make_uint2(pkbf(st[nb][0], st[nb][1]), pkbf(st[nb][2], st[nb][3]));
      bf16x8 ap0 = *(const bf16x8*)&pw[c*72 + g*8];
      bf16x8 ap1 = *(const bf16x8*)&pw[c*72 + 32 + g*8];
      // O += P * V
      #pragma unroll
      for (int vb = 0; vb < 4; ++vb){
        int rv = (vb*16 + c)*128;
        bf16x8 bv0 = *(const bf16x8*)(vl + base + rv + ((g << 4) ^ sw));
        bf16x8 bv1 = *(const bf16x8*)(vl + base + rv + (((4+g) << 4) ^ sw));
        acc[vb] = __builtin_amdgcn_mfma_f32_16x16x32_bf16(ap0, bv0, acc[vb], 0, 0, 0);
        acc[vb] = __builtin_amdgcn_mfma_f32_16x16x32_bf16(ap1, bv1, acc[vb], 0, 0, 0);
      }
      tilefac *= tstep2;
    }
  }

  // ---- combine parity partials, store ----
  if (e == 1){
    float* ob = Ob + j*(16*65);
    #pragma unroll
    for (int vb = 0; vb < 4; ++vb)
      #pragma unroll
      for (int r = 0; r < 4; ++r)
        ob[(g*4+r)*65 + vb*16 + c] = acc[vb][r];
  }
  __syncthreads();
  if (e == 0){
    const float* ob = Ob + j*(16*65);
    float* op = out + (boff + btile*64 + j*16 + g*4)*64;
    #pragma unroll
    for (int vb = 0; vb < 4; ++vb)
      #pragma unroll
      for (int r = 0; r < 4; ++r)
        op[r*64 + vb*16 + c] = acc[vb][r] + ob[(g*4+r)*65 + vb*16 + c];
  }
}

__global__ __launch_bounds__(512, 2) void retention_fused(
    const float* __restrict__ Q, const float* __restrict__ K,
    const float* __restrict__ V, float* __restrict__ out)
{
  __shared__ __align__(16) ushort klds[NTMAX][64][64];   // 48 KB
  __shared__ __align__(16) ushort vlds[NTMAX][64][64];   // 48 KB
  __shared__ __align__(16) ushort Pbuf[8][16][72];       // 18 KB
  __shared__ __align__(16) float  Obuf[4][16][65];       // 16.25 KB

  int bx = blockIdx.x;
  int b = bx >> 6, btile = bx & 63;
  int t0 = btile >= BAND ? btile - BAND : 0;
  int nt = btile - t0 + 1;
  size_t boff = (size_t)b * SEQ;
  if (nt == NTMAX)
    body<NTMAX>(nt, t0, boff, btile, threadIdx.x, Q, K, V, out,
                (char*)klds, (char*)vlds, &Pbuf[0][0][0], &Obuf[0][0][0]);
  else
    body<0>(nt, t0, boff, btile, threadIdx.x, Q, K, V, out,
            (char*)klds, (char*)vlds, &Pbuf[0][0][0], &Obuf[0][0][0]);
}

extern "C" void kernel_launch(void* const* d_in, const int* in_sizes, int n_in,
                              void* d_out, int out_size, void* d_ws, size_t ws_size,
                              hipStream_t stream){
  (void)in_sizes; (void)n_in; (void)out_size; (void)d_ws; (void)ws_size;
  const float* Q = (const float*)d_in[0];
  const float* K = (const float*)d_in[1];
  const float* V = (const float*)d_in[2];
  float* out = (float*)d_out;
  hipLaunchKernelGGL(retention_fused, dim3(256), dim3(512), 0, stream, Q, K, V, out);
}

// Round 7
// 12.620 us; speedup vs baseline: 2.0675x; 1.3571x over previous
//
#include <hip/hip_runtime.h>

typedef short bf16x8 __attribute__((ext_vector_type(8)));
typedef float f32x4 __attribute__((ext_vector_type(4)));

#define LG2G (-0.045803689613125f)   /* log2(0.96875) */
#define SEQ 4096
#define BAND 5                       /* m-tiles of 64 kept before the diagonal */
#define NTMAX (BAND + 1)

__device__ __forceinline__ unsigned pkbf(float a, float b){
  unsigned r; asm("v_cvt_pk_bf16_f32 %0, %1, %2" : "=v"(r) : "v"(a), "v"(b)); return r;
}
__device__ __forceinline__ unsigned rot_pack(float x0, float x1, float s, float c){
  return pkbf(x0*c - x1*s, x1*c + x0*s);
}
__device__ __forceinline__ float hw_sin(float rev){ float r; asm("v_sin_f32 %0, %1":"=v"(r):"v"(rev)); return r; }
__device__ __forceinline__ float hw_cos(float rev){ float r; asm("v_cos_f32 %0, %1":"=v"(r):"v"(rev)); return r; }

// Single fused kernel. grid 256; XCD-swizzled so each XCD owns 32 CONTIGUOUS
// logical btiles (band-overlapped K/V tiles then share one XCD's L2).
// block 512 = 8 waves = (strip j 0..3) x (tile-parity e 0..1). Self-staging:
//   q  -> registers; k' -> klds (xpos*gamma^-(m&63), XOR-swizzled);
//   V  -> vlds (bf16 transposed [v][m], XOR-swizzled).
// Phase 2 barrier-free (private per-wave P strips); one final combine barrier.
template<int NTC>
__device__ __forceinline__ void body(
    int nt, int t0, size_t boff, int btile, int t,
    const float* __restrict__ Q, const float* __restrict__ K,
    const float* __restrict__ V, float* __restrict__ out,
    char* kl, char* vl, ushort* Pb, float* Ob)
{
  int wave = t >> 6, lane = t & 63;
  int j = wave >> 1, e = wave & 1;
  int g = lane >> 4, c = lane & 15;
  const int NITER = NTC ? NTC : nt;

  // ---- phase 1A: q fragments straight to registers ----
  bf16x8 bq0, bq1;
  {
    int qrow = btile*64 + j*16 + c;
    const float* qp = Q + (boff + qrow)*64;
    float4 a0 = *(const float4*)(qp + g*8);
    float4 a1 = *(const float4*)(qp + g*8 + 4);
    float4 a2 = *(const float4*)(qp + 32 + g*8);
    float4 a3 = *(const float4*)(qp + 32 + g*8 + 4);
    float fs = (float)qrow;
    float qg = exp2f((float)(j*16 + c) * LG2G);      // gamma^(row&63)
    float p0[8] = {a0.x,a0.y,a0.z,a0.w,a1.x,a1.y,a1.z,a1.w};
    float p1[8] = {a2.x,a2.y,a2.z,a2.w,a3.x,a3.y,a3.z,a3.w};
    union { unsigned u[4]; bf16x8 v; } U0, U1;
    #pragma unroll
    for (int u = 0; u < 4; ++u){
      {
        int i = g*4 + u;
        float lb = log2f(((float)(2*i) + 25.6f) * (1.0f/89.6f));
        float sc = exp2f(lb * fs * (1.0f/512.0f)) * qg;
        float rev = fs * exp2f((float)i * -0.4152410118609203f) * 0.15915494309189535f;
        rev -= floorf(rev);
        U0.u[u] = rot_pack(p0[2*u], p0[2*u+1], hw_sin(rev)*sc, hw_cos(rev)*sc);
      }
      {
        int i = 16 + g*4 + u;
        float lb = log2f(((float)(2*i) + 25.6f) * (1.0f/89.6f));
        float sc = exp2f(lb * fs * (1.0f/512.0f)) * qg;
        float rev = fs * exp2f((float)i * -0.4152410118609203f) * 0.15915494309189535f;
        rev -= floorf(rev);
        U1.u[u] = rot_pack(p1[2*u], p1[2*u+1], hw_sin(rev)*sc, hw_cos(rev)*sc);
      }
    }
    bq0 = U0.v; bq1 = U1.v;
  }

  // ---- phase 1B: k tiles -> klds (xpos * gamma^-(row), swizzled) ----
  // Per-tile fs advances by 64 -> exp2 becomes a multiplicative recurrence,
  // rev an additive one: one v_exp saved per pair per tile.
  {
    int krow = t >> 3, dk = t & 7;                   // row 0..63, 8-float d-chunk
    float kfold = exp2f((float)(-krow) * LG2G);      // gamma^-(m&63)
    float fs0 = (float)(t0*64 + krow);
    float cur[4], stp[4], rev[4], rstep[4];
    #pragma unroll
    for (int u = 0; u < 4; ++u){
      int i = dk*4 + u;
      float lbn = log2f(((float)(2*i) + 25.6f) * (1.0f/89.6f)) * (-1.0f/512.0f);
      cur[u] = exp2f(lbn * fs0) * kfold;             // (1/scale) * gamma^-(row)
      stp[u] = exp2f(lbn * 64.0f);
      float ivf = exp2f((float)i * -0.4152410118609203f) * 0.15915494309189535f;
      rev[u] = fs0 * ivf;
      rstep[u] = 64.0f * ivf;
    }
    int woff = krow*128 + ((dk ^ (krow & 7)) << 4);  // XOR swizzle, 16B units
    #pragma unroll
    for (int ttl = 0; ttl < NITER; ++ttl){
      const float* kp = K + (boff + (size_t)(t0 + ttl)*64 + krow)*64 + dk*8;
      float4 b0 = *(const float4*)kp;
      float4 b1 = *(const float4*)(kp + 4);
      float px[8] = {b0.x,b0.y,b0.z,b0.w,b1.x,b1.y,b1.z,b1.w};
      unsigned w[4];
      #pragma unroll
      for (int u = 0; u < 4; ++u){
        float rv = rev[u] - floorf(rev[u]);
        w[u] = rot_pack(px[2*u], px[2*u+1], hw_sin(rv)*cur[u], hw_cos(rv)*cur[u]);
        cur[u] *= stp[u];
        rev[u] += rstep[u];
      }
      *(uint4*)(kl + ttl*8192 + woff) = make_uint4(w[0],w[1],w[2],w[3]);
    }
  }

  // ---- phase 1C: V tiles -> vlds transposed [v][m] (swizzled) ----
  {
    #pragma unroll
    for (int pass = 0; pass < 3; ++pass){
      int u = t + pass*512;
      int tile = u >> 8;
      if (tile < NITER){
        int rem = u & 255, m4 = rem >> 4, v4 = rem & 15;
        const float* vp = V + (boff + (size_t)(t0 + tile)*64 + m4*4)*64 + v4*4;
        float4 r0 = *(const float4*)vp;
        float4 r1 = *(const float4*)(vp + 64);
        float4 r2 = *(const float4*)(vp + 128);
        float4 r3 = *(const float4*)(vp + 192);
        float f0[4]={r0.x,r0.y,r0.z,r0.w}, f1[4]={r1.x,r1.y,r1.z,r1.w};
        float f2[4]={r2.x,r2.y,r2.z,r2.w}, f3[4]={r3.x,r3.y,r3.z,r3.w};
        #pragma unroll
        for (int jv = 0; jv < 4; ++jv){
          int v = v4*4 + jv;
          int off = tile*8192 + v*128 + (((m4 >> 1) ^ (v & 7)) << 4) + ((m4 & 1) << 3);
          *(uint2*)(vl + off) = make_uint2(pkbf(f0[jv], f1[jv]), pkbf(f2[jv], f3[jv]));
        }
      }
    }
  }
  __syncthreads();

  // ---- phase 2: barrier-free banded retention ----
  int sw = (c & 7) << 4;
  ushort* pw = Pb + wave * (16*72);                  // private P strip [16][72]
  float tilefac = exp2f((float)(64*(nt - 1 - e)) * LG2G);
  const float tstep2 = exp2f(-128.0f * LG2G);        // gamma^-128 (2-tile stride)
  f32x4 acc[4];
  #pragma unroll
  for (int vb = 0; vb < 4; ++vb) acc[vb] = (f32x4)0.0f;

  #pragma unroll
  for (int it = 0; it < (NTC ? (NTC+1)/2 : 3); ++it){
    int ttl = e + it*2;
    if (NTC ? true : (ttl < nt)){
      int base = ttl*8192;
      // S''^T = mfma(k', q'): lane (g,c) -> S''[qrow c][m = nb*16 + g*4 + r]
      f32x4 st[4];
      #pragma unroll
      for (int nb = 0; nb < 4; ++nb){
        int ro = (nb*16 + c)*128;
        bf16x8 ak0 = *(const bf16x8*)(kl + base + ro + ((g << 4) ^ sw));
        bf16x8 ak1 = *(const bf16x8*)(kl + base + ro + (((4+g) << 4) ^ sw));
        f32x4 z = (f32x4)0.0f;
        z = __builtin_amdgcn_mfma_f32_16x16x32_bf16(ak0, bq0, z, 0, 0, 0);
        z = __builtin_amdgcn_mfma_f32_16x16x32_bf16(ak1, bq1, z, 0, 0, 0);
        st[nb] = z;
      }
      #pragma unroll
      for (int nb = 0; nb < 4; ++nb)
        #pragma unroll
        for (int r = 0; r < 4; ++r) st[nb][r] *= tilefac;
      if (NTC ? (ttl == NTC-1) : (ttl == nt-1)){     // causal mask, diagonal only
        int qrl = j*16 + c;
        #pragma unroll
        for (int nb = 0; nb < 4; ++nb)
          #pragma unroll
          for (int r = 0; r < 4; ++r)
            if (qrl < nb*16 + g*4 + r) st[nb][r] = 0.0f;
      }
      // P -> private LDS strip (same-wave round trip, no barrier)
      #pragma unroll
      for (int nb = 0; nb < 4; ++nb)
        *(uint2*)&pw[c*72 + nb*16 + g*4] =
            make_uint2(pkbf(st[nb][0], st[nb][1]), pkbf(st[nb][2], st[nb][3]));
      bf16x8 ap0 = *(const bf16x8*)&pw[c*72 + g*8];
      bf16x8 ap1 = *(const bf16x8*)&pw[c*72 + 32 + g*8];
      // O += P * V
      #pragma unroll
      for (int vb = 0; vb < 4; ++vb){
        int rv = (vb*16 + c)*128;
        bf16x8 bv0 = *(const bf16x8*)(vl + base + rv + ((g << 4) ^ sw));
        bf16x8 bv1 = *(const bf16x8*)(vl + base + rv + (((4+g) << 4) ^ sw));
        acc[vb] = __builtin_amdgcn_mfma_f32_16x16x32_bf16(ap0, bv0, acc[vb], 0, 0, 0);
        acc[vb] = __builtin_amdgcn_mfma_f32_16x16x32_bf16(ap1, bv1, acc[vb], 0, 0, 0);
      }
      tilefac *= tstep2;
    }
  }

  // ---- combine parity partials, store ----
  if (e == 1){
    float* ob = Ob + j*(16*65);
    #pragma unroll
    for (int vb = 0; vb < 4; ++vb)
      #pragma unroll
      for (int r = 0; r < 4; ++r)
        ob[(g*4+r)*65 + vb*16 + c] = acc[vb][r];
  }
  __syncthreads();
  if (e == 0){
    const float* ob = Ob + j*(16*65);
    float* op = out + (boff + btile*64 + j*16 + g*4)*64;
    #pragma unroll
    for (int vb = 0; vb < 4; ++vb)
      #pragma unroll
      for (int r = 0; r < 4; ++r)
        op[r*64 + vb*16 + c] = acc[vb][r] + ob[(g*4+r)*65 + vb*16 + c];
  }
}

__global__ __launch_bounds__(512, 2) void retention_fused(
    const float* __restrict__ Q, const float* __restrict__ K,
    const float* __restrict__ V, float* __restrict__ out)
{
  __shared__ __align__(16) ushort klds[NTMAX][64][64];   // 48 KB
  __shared__ __align__(16) ushort vlds[NTMAX][64][64];   // 48 KB
  __shared__ __align__(16) ushort Pbuf[8][16][72];       // 18 KB
  __shared__ __align__(16) float  Obuf[4][16][65];       // 16.25 KB

  // XCD-aware bijective swizzle (256 = 8 XCDs x 32): XCD (bx&7) gets the
  // contiguous logical chunk [(bx&7)*32, +32) so band-overlapped K/V tiles
  // are fetched once per XCD L2 instead of once per XCD touched.
  int bx = blockIdx.x;
  int l = (bx & 7) * 32 + (bx >> 3);
  int b = l >> 6, btile = l & 63;
  int t0 = btile >= BAND ? btile - BAND : 0;
  int nt = btile - t0 + 1;
  size_t boff = (size_t)b * SEQ;
  if (nt == NTMAX)
    body<NTMAX>(nt, t0, boff, btile, threadIdx.x, Q, K, V, out,
                (char*)klds, (char*)vlds, &Pbuf[0][0][0], &Obuf[0][0][0]);
  else
    body<0>(nt, t0, boff, btile, threadIdx.x, Q, K, V, out,
            (char*)klds, (char*)vlds, &Pbuf[0][0][0], &Obuf[0][0][0]);
}

extern "C" void kernel_launch(void* const* d_in, const int* in_sizes, int n_in,
                              void* d_out, int out_size, void* d_ws, size_t ws_size,
                              hipStream_t stream){
  (void)in_sizes; (void)n_in; (void)out_size; (void)d_ws; (void)ws_size;
  const float* Q = (const float*)d_in[0];
  const float* K = (const float*)d_in[1];
  const float* V = (const float*)d_in[2];
  float* out = (float*)d_out;
  hipLaunchKernelGGL(retention_fused, dim3(256), dim3(512), 0, stream, Q, K, V, out);
}